// Round 1
// baseline (719.085 us; speedup 1.0000x reference)
//
#include <hip/hip_runtime.h>
#include <hip/hip_bf16.h>

// Problem constants (from reference)
constexpr int N  = 50000;    // nodes
constexpr int E  = 800000;   // edges (self-loops added implicitly)
constexpr int F0 = 128;      // in channels
constexpr int H1 = 32;       // heads layer 1
constexpr int C1 = 8;        // hid channels per head
constexpr int F1 = H1 * C1;  // 256
constexpr int F2 = 64;       // out channels
constexpr float NEG_SLOPE = 0.2f;

__device__ __forceinline__ float leaky(float e) { return e > 0.f ? e : NEG_SLOPE * e; }

// ---------------------------------------------------------------------------
// 0. Detect edge_index dtype: int64 (ref) vs int32 (JAX x64-off / harness).
//    If data is int32, reading as u64 combines value pairs -> huge numbers.
__global__ void k_detect(const unsigned long long* __restrict__ p, int* __restrict__ flag) {
    __shared__ int bad;
    if (threadIdx.x == 0) bad = 0;
    __syncthreads();
    unsigned long long v = p[threadIdx.x];   // first 1024 u64 = 8KB, safely in-bounds
    if (v >= (unsigned long long)N) atomicOr(&bad, 1);
    __syncthreads();
    if (threadIdx.x == 0) *flag = bad ? 0 : 1;   // 1 == int64
}

__device__ __forceinline__ int load_idx(const void* ei, long long i, int is64) {
    return is64 ? (int)((const long long*)ei)[i] : ((const int*)ei)[i];
}

// ---------------------------------------------------------------------------
// 1. CSR build by dst
__global__ void k_count(const void* __restrict__ ei, const int* __restrict__ flag,
                        int* __restrict__ deg) {
    int e = blockIdx.x * blockDim.x + threadIdx.x;
    if (e >= E) return;
    int is64 = *flag;
    int dst = load_idx(ei, (long long)E + e, is64);
    atomicAdd(&deg[dst], 1);
}

__global__ void k_scan(const int* __restrict__ deg, int* __restrict__ rs, int n) {
    __shared__ int sh[1024];
    __shared__ int carry;
    if (threadIdx.x == 0) carry = 0;
    __syncthreads();
    for (int base = 0; base < n; base += 1024) {
        int i = base + threadIdx.x;
        int v = (i < n) ? deg[i] : 0;
        sh[threadIdx.x] = v;
        __syncthreads();
        for (int off = 1; off < 1024; off <<= 1) {
            int t = (threadIdx.x >= off) ? sh[threadIdx.x - off] : 0;
            __syncthreads();
            sh[threadIdx.x] += t;
            __syncthreads();
        }
        if (i < n) rs[i] = carry + sh[threadIdx.x] - v;   // exclusive
        __syncthreads();
        if (threadIdx.x == 1023) carry += sh[1023];
        __syncthreads();
    }
    if (threadIdx.x == 0) rs[n] = carry;
}

__global__ void k_scatter(const void* __restrict__ ei, const int* __restrict__ flag,
                          const int* __restrict__ rs, int* __restrict__ fill,
                          int* __restrict__ csr) {
    int e = blockIdx.x * blockDim.x + threadIdx.x;
    if (e >= E) return;
    int is64 = *flag;
    int src = load_idx(ei, e, is64);
    int dst = load_idx(ei, (long long)E + e, is64);
    int pos = rs[dst] + atomicAdd(&fill[dst], 1);
    csr[pos] = src;
}

// ---------------------------------------------------------------------------
// 2. GEMM1: h1 = x @ W1  [50000,128]@[128,256]; fused alpha_src1/alpha_dst1.
//    16 rows/block, 256 threads (one output column each), x tile in LDS.
__global__ __launch_bounds__(256) void k_gemm1(
        const float* __restrict__ x, const float* __restrict__ W,
        const float* __restrict__ as1, const float* __restrict__ ad1,
        float* __restrict__ h1, float* __restrict__ asrc1, float* __restrict__ adst1) {
    __shared__ float xs[16][F0];
    int r0 = blockIdx.x * 16;       // 50000 % 16 == 0  -> always full tile
    int t = threadIdx.x;
    for (int i = t; i < 16 * F0; i += 256)
        xs[i >> 7][i & 127] = x[(size_t)(r0 + (i >> 7)) * F0 + (i & 127)];
    __syncthreads();
    float acc[16];
#pragma unroll
    for (int r = 0; r < 16; r++) acc[r] = 0.f;
    for (int k = 0; k < F0; k++) {
        float wv = W[k * F1 + t];
#pragma unroll
        for (int r = 0; r < 16; r++) acc[r] = fmaf(xs[r][k], wv, acc[r]);
    }
    int h = t >> 3, c = t & 7;
    float aw_s = as1[h * 8 + c], aw_d = ad1[h * 8 + c];
#pragma unroll
    for (int r = 0; r < 16; r++) {
        h1[(size_t)(r0 + r) * F1 + t] = acc[r];
        float ps = acc[r] * aw_s, pd = acc[r] * aw_d;
#pragma unroll
        for (int o = 1; o < 8; o <<= 1) {
            ps += __shfl_xor(ps, o, 64);
            pd += __shfl_xor(pd, o, 64);
        }
        if (c == 0) {
            asrc1[(size_t)(r0 + r) * H1 + h] = ps;
            adst1[(size_t)(r0 + r) * H1 + h] = pd;
        }
    }
}

// ---------------------------------------------------------------------------
// 3. Edge pass layer 1: one block (256 thr) per dst node; thread = (head, chan).
//    Pass A: segment max (self loop included). Pass B: exp-weighted gather-sum.
__global__ __launch_bounds__(256) void k_edge1(
        const int* __restrict__ rs, const int* __restrict__ csr,
        const float* __restrict__ h1, const float* __restrict__ asrc,
        const float* __restrict__ adst, const float* __restrict__ b1,
        float* __restrict__ out) {
    int d = blockIdx.x;
    int t = threadIdx.x;
    int h = t >> 3;
    int beg = rs[d], end = rs[d + 1];
    float ad = adst[(size_t)d * H1 + h];
    float e_self = leaky(asrc[(size_t)d * H1 + h] + ad);
    float m = e_self;
    for (int i = beg; i < end; i++) {
        int s = csr[i];
        m = fmaxf(m, leaky(asrc[(size_t)s * H1 + h] + ad));
    }
    float ex = __expf(e_self - m);
    float den = ex;
    float acc = ex * h1[(size_t)d * F1 + t];
    for (int i = beg; i < end; i++) {
        int s = csr[i];
        float w = __expf(leaky(asrc[(size_t)s * H1 + h] + ad) - m);
        den += w;
        acc = fmaf(w, h1[(size_t)s * F1 + t], acc);
    }
    out[(size_t)d * F1 + t] = acc / (den + 1e-16f) + b1[t];
}

// ---------------------------------------------------------------------------
// 4. GEMM2: h2 = h1_att @ W2  [50000,256]@[256,64]; fused alpha2 (wave reduce).
//    32 rows/block, 256 threads = 4 waves; wave ty owns rows ty+4j, lane = col.
__global__ __launch_bounds__(256) void k_gemm2(
        const float* __restrict__ A, const float* __restrict__ W,
        const float* __restrict__ a2s, const float* __restrict__ a2d,
        float* __restrict__ h2, float* __restrict__ asrc2, float* __restrict__ adst2) {
    __shared__ float xs[32][F1];
    int r0 = blockIdx.x * 32;
    int t = threadIdx.x, ty = t >> 6, lane = t & 63;
    for (int i = t; i < 32 * F1; i += 256) {
        int r = i >> 8, c = i & 255, rr = r0 + r;
        xs[r][c] = (rr < N) ? A[(size_t)rr * F1 + c] : 0.f;
    }
    __syncthreads();
    float acc[8];
#pragma unroll
    for (int j = 0; j < 8; j++) acc[j] = 0.f;
    for (int k = 0; k < F1; k++) {
        float wv = W[k * F2 + lane];
#pragma unroll
        for (int j = 0; j < 8; j++) acc[j] = fmaf(xs[ty + 4 * j][k], wv, acc[j]);
    }
    float wsv = a2s[lane], wdv = a2d[lane];
#pragma unroll
    for (int j = 0; j < 8; j++) {
        int r = r0 + ty + 4 * j;
        float ps = acc[j] * wsv, pd = acc[j] * wdv;
#pragma unroll
        for (int o = 1; o < 64; o <<= 1) {
            ps += __shfl_xor(ps, o, 64);
            pd += __shfl_xor(pd, o, 64);
        }
        if (r < N) {
            h2[(size_t)r * F2 + lane] = acc[j];
            if (lane == 0) { asrc2[r] = ps; adst2[r] = pd; }
        }
    }
}

// ---------------------------------------------------------------------------
// 5. Edge pass layer 2 (H=1, C=64): one wave per node, lane = channel.
//    Fused bias + sigmoid -> d_out.
__global__ __launch_bounds__(256) void k_edge2(
        const int* __restrict__ rs, const int* __restrict__ csr,
        const float* __restrict__ h2, const float* __restrict__ asrc,
        const float* __restrict__ adst, const float* __restrict__ b2,
        float* __restrict__ out) {
    int d = blockIdx.x * 4 + (threadIdx.x >> 6);
    int lane = threadIdx.x & 63;
    if (d >= N) return;
    int beg = rs[d], end = rs[d + 1];
    float ad = adst[d];
    float e_self = leaky(asrc[d] + ad);
    float m = e_self;
    for (int i = beg; i < end; i++) m = fmaxf(m, leaky(asrc[csr[i]] + ad));
    float ex = __expf(e_self - m);
    float den = ex;
    float acc = ex * h2[(size_t)d * F2 + lane];
    for (int i = beg; i < end; i++) {
        int s = csr[i];
        float w = __expf(leaky(asrc[s] + ad) - m);
        den += w;
        acc = fmaf(w, h2[(size_t)s * F2 + lane], acc);
    }
    float v = acc / (den + 1e-16f) + b2[lane];
    out[(size_t)d * F2 + lane] = 1.f / (1.f + __expf(-v));
}

// ---------------------------------------------------------------------------
extern "C" void kernel_launch(void* const* d_in, const int* in_sizes, int n_in,
                              void* d_out, int out_size, void* d_ws, size_t ws_size,
                              hipStream_t stream) {
    const float* x   = (const float*)d_in[0];
    const void*  ei  = d_in[1];
    const float* W1  = (const float*)d_in[2];
    const float* as1 = (const float*)d_in[3];
    const float* ad1 = (const float*)d_in[4];
    const float* b1  = (const float*)d_in[5];
    const float* W2  = (const float*)d_in[6];
    const float* a2s = (const float*)d_in[7];
    const float* a2d = (const float*)d_in[8];
    const float* b2  = (const float*)d_in[9];
    float* out = (float*)d_out;

    char* w = (char*)d_ws;
    size_t off = 0;
    auto alloc = [&](size_t bytes) {
        void* p = w + off;
        off = (off + bytes + 255) & ~(size_t)255;
        return p;
    };
    int*   flag  = (int*)alloc(4);
    int*   deg   = (int*)alloc((size_t)N * 4);
    int*   fill  = (int*)alloc((size_t)N * 4);
    int*   rs    = (int*)alloc((size_t)(N + 1) * 4);
    int*   csr   = (int*)alloc((size_t)E * 4);
    float* h1    = (float*)alloc((size_t)N * F1 * 4);
    float* h1a   = (float*)alloc((size_t)N * F1 * 4);
    float* h2    = (float*)alloc((size_t)N * F2 * 4);
    float* asrc1 = (float*)alloc((size_t)N * H1 * 4);
    float* adst1 = (float*)alloc((size_t)N * H1 * 4);
    float* asrc2 = (float*)alloc((size_t)N * 4);
    float* adst2 = (float*)alloc((size_t)N * 4);

    hipMemsetAsync(deg, 0, (size_t)N * 4, stream);
    hipMemsetAsync(fill, 0, (size_t)N * 4, stream);

    k_detect<<<1, 1024, 0, stream>>>((const unsigned long long*)ei, flag);
    k_count<<<(E + 255) / 256, 256, 0, stream>>>(ei, flag, deg);
    k_scan<<<1, 1024, 0, stream>>>(deg, rs, N);
    k_scatter<<<(E + 255) / 256, 256, 0, stream>>>(ei, flag, rs, fill, csr);

    k_gemm1<<<N / 16, 256, 0, stream>>>(x, W1, as1, ad1, h1, asrc1, adst1);
    k_edge1<<<N, 256, 0, stream>>>(rs, csr, h1, asrc1, adst1, b1, h1a);
    k_gemm2<<<(N + 31) / 32, 256, 0, stream>>>(h1a, W2, a2s, a2d, h2, asrc2, adst2);
    k_edge2<<<N / 4, 256, 0, stream>>>(rs, csr, h2, asrc2, adst2, b2, out);
}

// Round 2
// 478.761 us; speedup vs baseline: 1.5020x; 1.5020x over previous
//
#include <hip/hip_runtime.h>
#include <hip/hip_bf16.h>

// Problem constants (from reference)
constexpr int N  = 50000;    // nodes
constexpr int E  = 800000;   // edges (self-loops added implicitly)
constexpr int F0 = 128;      // in channels
constexpr int H1 = 32;       // heads layer 1
constexpr int C1 = 8;        // hid channels per head
constexpr int F1 = H1 * C1;  // 256
constexpr int F2 = 64;       // out channels
constexpr int NB = (N + 255) / 256;  // 196 scan blocks
constexpr float NEG_SLOPE = 0.2f;

__device__ __forceinline__ float leaky(float e) { return e > 0.f ? e : NEG_SLOPE * e; }

// ---------------------------------------------------------------------------
// 0. Detect edge_index dtype: int64 (ref) vs int32.
__global__ void k_detect(const unsigned long long* __restrict__ p, int* __restrict__ flag) {
    __shared__ int bad;
    if (threadIdx.x == 0) bad = 0;
    __syncthreads();
    unsigned long long v = p[threadIdx.x];
    if (v >= (unsigned long long)N) atomicOr(&bad, 1);
    __syncthreads();
    if (threadIdx.x == 0) *flag = bad ? 0 : 1;   // 1 == int64
}

__device__ __forceinline__ int load_idx(const void* ei, long long i, int is64) {
    return is64 ? (int)((const long long*)ei)[i] : ((const int*)ei)[i];
}

// ---------------------------------------------------------------------------
// 1. CSR build by dst: count -> hierarchical scan -> scatter
__global__ void k_count(const void* __restrict__ ei, const int* __restrict__ flag,
                        int* __restrict__ deg) {
    int e = blockIdx.x * blockDim.x + threadIdx.x;
    if (e >= E) return;
    int is64 = *flag;
    int dst = load_idx(ei, (long long)E + e, is64);
    atomicAdd(&deg[dst], 1);
}

__global__ __launch_bounds__(256) void k_bsum(const int* __restrict__ deg, int* __restrict__ bsum) {
    int b = blockIdx.x, t = threadIdx.x, i = b * 256 + t;
    int v = (i < N) ? deg[i] : 0;
#pragma unroll
    for (int o = 1; o < 64; o <<= 1) v += __shfl_xor(v, o, 64);
    __shared__ int sw[4];
    if ((t & 63) == 0) sw[t >> 6] = v;
    __syncthreads();
    if (t == 0) bsum[b] = sw[0] + sw[1] + sw[2] + sw[3];
}

__global__ __launch_bounds__(256) void k_bscan(int* __restrict__ bsum, int* __restrict__ rsN) {
    int t = threadIdx.x, lane = t & 63, wy = t >> 6;
    int v = (t < NB) ? bsum[t] : 0;
    int inc = v;
#pragma unroll
    for (int o = 1; o < 64; o <<= 1) { int u = __shfl_up(inc, o, 64); if (lane >= o) inc += u; }
    __shared__ int wtot[4];
    if (lane == 63) wtot[wy] = inc;
    __syncthreads();
    int offs = 0;
    for (int k = 0; k < wy; k++) offs += wtot[k];
    int excl = offs + inc - v;
    if (t < NB) bsum[t] = excl;
    if (t == NB - 1) *rsN = excl + v;   // grand total -> rs[N]
}

__global__ __launch_bounds__(256) void k_rs(const int* __restrict__ deg,
                                            const int* __restrict__ bsum, int* __restrict__ rs) {
    int b = blockIdx.x, t = threadIdx.x, i = b * 256 + t;
    int lane = t & 63, wy = t >> 6;
    int v = (i < N) ? deg[i] : 0;
    int inc = v;
#pragma unroll
    for (int o = 1; o < 64; o <<= 1) { int u = __shfl_up(inc, o, 64); if (lane >= o) inc += u; }
    __shared__ int wtot[4];
    if (lane == 63) wtot[wy] = inc;
    __syncthreads();
    int offs = bsum[b];
    for (int k = 0; k < wy; k++) offs += wtot[k];
    if (i < N) rs[i] = offs + inc - v;
}

__global__ void k_scatter(const void* __restrict__ ei, const int* __restrict__ flag,
                          const int* __restrict__ rs, int* __restrict__ fill,
                          int* __restrict__ csr) {
    int e = blockIdx.x * blockDim.x + threadIdx.x;
    if (e >= E) return;
    int is64 = *flag;
    int src = load_idx(ei, e, is64);
    int dst = load_idx(ei, (long long)E + e, is64);
    int pos = rs[dst] + atomicAdd(&fill[dst], 1);
    csr[pos] = src;
}

// ---------------------------------------------------------------------------
// 2. GEMM1: h1 = x @ W1  [50000,128]@[128,256]; fused alpha_src1/alpha_dst1.
//    32 rows/block, 256 threads (one output column each), x tile in LDS.
__global__ __launch_bounds__(256) void k_gemm1(
        const float* __restrict__ x, const float* __restrict__ W,
        const float* __restrict__ as1, const float* __restrict__ ad1,
        float* __restrict__ h1, float* __restrict__ asrc1, float* __restrict__ adst1) {
    __shared__ float xs[32][F0];
    int r0 = blockIdx.x * 32;
    int t = threadIdx.x;
    for (int i = t; i < 32 * F0; i += 256) {
        int r = i >> 7, c = i & 127, rr = r0 + r;
        xs[r][c] = (rr < N) ? x[(size_t)rr * F0 + c] : 0.f;
    }
    __syncthreads();
    float acc[32];
#pragma unroll
    for (int r = 0; r < 32; r++) acc[r] = 0.f;
    for (int k = 0; k < F0; k++) {
        float wv = W[k * F1 + t];
#pragma unroll
        for (int r = 0; r < 32; r++) acc[r] = fmaf(xs[r][k], wv, acc[r]);
    }
    int h = t >> 3, c = t & 7;
    float aw_s = as1[h * 8 + c], aw_d = ad1[h * 8 + c];
#pragma unroll
    for (int r = 0; r < 32; r++) {
        int rr = r0 + r;
        if (rr >= N) break;
        h1[(size_t)rr * F1 + t] = acc[r];
        float ps = acc[r] * aw_s, pd = acc[r] * aw_d;
#pragma unroll
        for (int o = 1; o < 8; o <<= 1) {
            ps += __shfl_xor(ps, o, 64);
            pd += __shfl_xor(pd, o, 64);
        }
        if (c == 0) {
            asrc1[(size_t)rr * H1 + h] = ps;
            adst1[(size_t)rr * H1 + h] = pd;
        }
    }
}

// ---------------------------------------------------------------------------
// 3. Edge pass layer 1: one block (256 thr) per dst node.
//    Single pass, no max subtraction (scores bounded, exp safe in fp32).
//    Per 64-edge chunk: csr -> LDS; cooperative score phase computes
//    w = exp(leaky(asrc[s][h]+ad[h])) ONCE per (edge,head) (coalesced 128B
//    asrc rows); accumulate phase reads w from LDS (broadcast) + 1KB h1 rows.
__global__ __launch_bounds__(256) void k_edge1(
        const int* __restrict__ rs, const int* __restrict__ csr,
        const float* __restrict__ h1, const float* __restrict__ asrc,
        const float* __restrict__ adst, const float* __restrict__ b1,
        float* __restrict__ out) {
    __shared__ int   s_sh[64];
    __shared__ float ws[64][33];   // pad 33: <=2-way banks in both phases
    int d = blockIdx.x;
    int t = threadIdx.x;
    int h8 = t >> 3;               // head for accumulate phase
    int hs = t & 31;               // head for score phase
    int beg = rs[d], end = rs[d + 1];

    float ad_score = adst[(size_t)d * H1 + hs];
    // self loop (redundant per c-lane, trivial: once per node)
    float ads = adst[(size_t)d * H1 + h8];
    float wself = __expf(leaky(asrc[(size_t)d * H1 + h8] + ads));
    float den = wself;
    float acc = wself * h1[(size_t)d * F1 + t];

    for (int base = beg; base < end; base += 64) {
        int cnt = min(64, end - base);
        if (t < cnt) s_sh[t] = csr[base + t];
        __syncthreads();
        // scores: 256 threads cover 8 edges x 32 heads per iteration
        for (int j = t; j < cnt * 32; j += 256) {
            int i = j >> 5;                     // j&31 == hs
            int s = s_sh[i];
            ws[i][hs] = __expf(leaky(asrc[(size_t)s * H1 + hs] + ad_score));
        }
        __syncthreads();
#pragma unroll 4
        for (int i = 0; i < cnt; i++) {
            float wv = ws[i][h8];
            den += wv;
            acc = fmaf(wv, h1[(size_t)s_sh[i] * F1 + t], acc);
        }
        __syncthreads();
    }
    out[(size_t)d * F1 + t] = acc / (den + 1e-16f) + b1[t];
}

// ---------------------------------------------------------------------------
// 4. GEMM2: h2 = h1_att @ W2  [50000,256]@[256,64]; fused alpha2.
__global__ __launch_bounds__(256) void k_gemm2(
        const float* __restrict__ A, const float* __restrict__ W,
        const float* __restrict__ a2s, const float* __restrict__ a2d,
        float* __restrict__ h2, float* __restrict__ asrc2, float* __restrict__ adst2) {
    __shared__ float xs[32][F1];
    int r0 = blockIdx.x * 32;
    int t = threadIdx.x, ty = t >> 6, lane = t & 63;
    for (int i = t; i < 32 * F1; i += 256) {
        int r = i >> 8, c = i & 255, rr = r0 + r;
        xs[r][c] = (rr < N) ? A[(size_t)rr * F1 + c] : 0.f;
    }
    __syncthreads();
    float acc[8];
#pragma unroll
    for (int j = 0; j < 8; j++) acc[j] = 0.f;
    for (int k = 0; k < F1; k++) {
        float wv = W[k * F2 + lane];
#pragma unroll
        for (int j = 0; j < 8; j++) acc[j] = fmaf(xs[ty + 4 * j][k], wv, acc[j]);
    }
    float wsv = a2s[lane], wdv = a2d[lane];
#pragma unroll
    for (int j = 0; j < 8; j++) {
        int r = r0 + ty + 4 * j;
        float ps = acc[j] * wsv, pd = acc[j] * wdv;
#pragma unroll
        for (int o = 1; o < 64; o <<= 1) {
            ps += __shfl_xor(ps, o, 64);
            pd += __shfl_xor(pd, o, 64);
        }
        if (r < N) {
            h2[(size_t)r * F2 + lane] = acc[j];
            if (lane == 0) { asrc2[r] = ps; adst2[r] = pd; }
        }
    }
}

// ---------------------------------------------------------------------------
// 5. Edge pass layer 2 (H=1, C=64): one wave per node, lane = channel.
//    Single pass, no max. Per 64-edge chunk each lane computes one score,
//    then shfl-broadcast (readlane, uniform idx) in the accumulate loop.
__global__ __launch_bounds__(256) void k_edge2(
        const int* __restrict__ rs, const int* __restrict__ csr,
        const float* __restrict__ h2, const float* __restrict__ asrc,
        const float* __restrict__ adst, const float* __restrict__ b2,
        float* __restrict__ out) {
    int d = blockIdx.x * 4 + (threadIdx.x >> 6);
    int lane = threadIdx.x & 63;
    if (d >= N) return;
    int beg = rs[d], end = rs[d + 1];
    float ad = adst[d];
    float den = __expf(leaky(asrc[d] + ad));       // self loop
    float acc = den * h2[(size_t)d * F2 + lane];
    for (int base = beg; base < end; base += 64) {
        int cnt = min(64, end - base);
        int s = (lane < cnt) ? csr[base + lane] : 0;
        float w = (lane < cnt) ? __expf(leaky(asrc[s] + ad)) : 0.f;
        for (int i = 0; i < cnt; i++) {
            float wi = __shfl(w, i, 64);
            int   si = __shfl(s, i, 64);
            den += wi;
            acc = fmaf(wi, h2[(size_t)si * F2 + lane], acc);
        }
    }
    float v = acc / (den + 1e-16f) + b2[lane];
    out[(size_t)d * F2 + lane] = 1.f / (1.f + __expf(-v));
}

// ---------------------------------------------------------------------------
extern "C" void kernel_launch(void* const* d_in, const int* in_sizes, int n_in,
                              void* d_out, int out_size, void* d_ws, size_t ws_size,
                              hipStream_t stream) {
    const float* x   = (const float*)d_in[0];
    const void*  ei  = d_in[1];
    const float* W1  = (const float*)d_in[2];
    const float* as1 = (const float*)d_in[3];
    const float* ad1 = (const float*)d_in[4];
    const float* b1  = (const float*)d_in[5];
    const float* W2  = (const float*)d_in[6];
    const float* a2s = (const float*)d_in[7];
    const float* a2d = (const float*)d_in[8];
    const float* b2  = (const float*)d_in[9];
    float* out = (float*)d_out;

    char* w = (char*)d_ws;
    size_t off = 0;
    auto alloc = [&](size_t bytes) {
        void* p = w + off;
        off = (off + bytes + 255) & ~(size_t)255;
        return p;
    };
    int*   flag  = (int*)alloc(4);
    int*   deg   = (int*)alloc((size_t)N * 4);
    int*   fill  = (int*)alloc((size_t)N * 4);
    int*   rs    = (int*)alloc((size_t)(N + 1) * 4);
    int*   bsum  = (int*)alloc((size_t)NB * 4);
    int*   csr   = (int*)alloc((size_t)E * 4);
    float* h1    = (float*)alloc((size_t)N * F1 * 4);
    float* h1a   = (float*)alloc((size_t)N * F1 * 4);
    float* h2    = (float*)alloc((size_t)N * F2 * 4);
    float* asrc1 = (float*)alloc((size_t)N * H1 * 4);
    float* adst1 = (float*)alloc((size_t)N * H1 * 4);
    float* asrc2 = (float*)alloc((size_t)N * 4);
    float* adst2 = (float*)alloc((size_t)N * 4);

    hipMemsetAsync(deg, 0, (size_t)N * 4, stream);
    hipMemsetAsync(fill, 0, (size_t)N * 4, stream);

    k_detect<<<1, 1024, 0, stream>>>((const unsigned long long*)ei, flag);
    k_count<<<(E + 255) / 256, 256, 0, stream>>>(ei, flag, deg);
    k_bsum<<<NB, 256, 0, stream>>>(deg, bsum);
    k_bscan<<<1, 256, 0, stream>>>(bsum, rs + N);
    k_rs<<<NB, 256, 0, stream>>>(deg, bsum, rs);
    k_scatter<<<(E + 255) / 256, 256, 0, stream>>>(ei, flag, rs, fill, csr);

    k_gemm1<<<(N + 31) / 32, 256, 0, stream>>>(x, W1, as1, ad1, h1, asrc1, adst1);
    k_edge1<<<N, 256, 0, stream>>>(rs, csr, h1, asrc1, adst1, b1, h1a);
    k_gemm2<<<(N + 31) / 32, 256, 0, stream>>>(h1a, W2, a2s, a2d, h2, asrc2, adst2);
    k_edge2<<<(N + 3) / 4, 256, 0, stream>>>(rs, csr, h2, asrc2, adst2, b2, out);
}

// Round 3
// 332.949 us; speedup vs baseline: 2.1597x; 1.4379x over previous
//
#include <hip/hip_runtime.h>
#include <hip/hip_bf16.h>

constexpr int N  = 50000;
constexpr int E  = 800000;
constexpr int F0 = 128;
constexpr int H1 = 32;
constexpr int F1 = 256;      // H1*C1
constexpr int F2 = 64;
constexpr int NB = (N + 255) / 256;        // 196 scan blocks
constexpr int NPAD = 782 * 64;             // 50048, row pad for 64-row GEMM tiles
constexpr int XSZ  = N * F0;               // 6.4M
constexpr int W1SZ = F0 * F1;              // 32768
constexpr int W2SZ = F1 * F2;              // 16384
constexpr float NEG_SLOPE = 0.2f;

typedef unsigned short u16;
typedef unsigned int   u32;
typedef __attribute__((ext_vector_type(8))) short bf16x8;
typedef __attribute__((ext_vector_type(4))) float f32x4;

__device__ __forceinline__ float leaky(float e) { return e > 0.f ? e : NEG_SLOPE * e; }
__device__ __forceinline__ float bf2f(u16 u) {
    u32 v = ((u32)u) << 16;
    return __builtin_bit_cast(float, v);
}
__device__ __forceinline__ u16 f2bf(float f) {
    u32 u = __builtin_bit_cast(u32, f);
    u += 0x7fffu + ((u >> 16) & 1u);   // round-nearest-even
    return (u16)(u >> 16);
}

// ---------------------------------------------------------------------------
// 0. edge_index dtype detect (int64 vs int32)
__global__ void k_detect(const unsigned long long* __restrict__ p, int* __restrict__ flag) {
    __shared__ int bad;
    if (threadIdx.x == 0) bad = 0;
    __syncthreads();
    unsigned long long v = p[threadIdx.x];
    if (v >= (unsigned long long)N) atomicOr(&bad, 1);
    __syncthreads();
    if (threadIdx.x == 0) *flag = bad ? 0 : 1;
}
__device__ __forceinline__ int load_idx(const void* ei, long long i, int is64) {
    return is64 ? (int)((const long long*)ei)[i] : ((const int*)ei)[i];
}

// ---------------------------------------------------------------------------
// 1. CSR build by dst
__global__ void k_count(const void* __restrict__ ei, const int* __restrict__ flag,
                        int* __restrict__ deg) {
    int e = blockIdx.x * blockDim.x + threadIdx.x;
    if (e >= E) return;
    int dst = load_idx(ei, (long long)E + e, *flag);
    atomicAdd(&deg[dst], 1);
}
__global__ __launch_bounds__(256) void k_bsum(const int* __restrict__ deg, int* __restrict__ bsum) {
    int b = blockIdx.x, t = threadIdx.x, i = b * 256 + t;
    int v = (i < N) ? deg[i] : 0;
#pragma unroll
    for (int o = 1; o < 64; o <<= 1) v += __shfl_xor(v, o, 64);
    __shared__ int sw[4];
    if ((t & 63) == 0) sw[t >> 6] = v;
    __syncthreads();
    if (t == 0) bsum[b] = sw[0] + sw[1] + sw[2] + sw[3];
}
__global__ __launch_bounds__(256) void k_bscan(int* __restrict__ bsum, int* __restrict__ rsN) {
    int t = threadIdx.x, lane = t & 63, wy = t >> 6;
    int v = (t < NB) ? bsum[t] : 0;
    int inc = v;
#pragma unroll
    for (int o = 1; o < 64; o <<= 1) { int u = __shfl_up(inc, o, 64); if (lane >= o) inc += u; }
    __shared__ int wtot[4];
    if (lane == 63) wtot[wy] = inc;
    __syncthreads();
    int offs = 0;
    for (int k = 0; k < wy; k++) offs += wtot[k];
    int excl = offs + inc - v;
    if (t < NB) bsum[t] = excl;
    if (t == NB - 1) *rsN = excl + v;
}
__global__ __launch_bounds__(256) void k_rs(const int* __restrict__ deg,
                                            const int* __restrict__ bsum, int* __restrict__ rs) {
    int b = blockIdx.x, t = threadIdx.x, i = b * 256 + t;
    int lane = t & 63, wy = t >> 6;
    int v = (i < N) ? deg[i] : 0;
    int inc = v;
#pragma unroll
    for (int o = 1; o < 64; o <<= 1) { int u = __shfl_up(inc, o, 64); if (lane >= o) inc += u; }
    __shared__ int wtot[4];
    if (lane == 63) wtot[wy] = inc;
    __syncthreads();
    int offs = bsum[b];
    for (int k = 0; k < wy; k++) offs += wtot[k];
    if (i < N) rs[i] = offs + inc - v;
}
__global__ void k_scatter(const void* __restrict__ ei, const int* __restrict__ flag,
                          const int* __restrict__ rs, int* __restrict__ fill,
                          int* __restrict__ csr) {
    int e = blockIdx.x * blockDim.x + threadIdx.x;
    if (e >= E) return;
    int is64 = *flag;
    int src = load_idx(ei, e, is64);
    int dst = load_idx(ei, (long long)E + e, is64);
    int pos = rs[dst] + atomicAdd(&fill[dst], 1);
    csr[pos] = src;
}

// ---------------------------------------------------------------------------
// 2. Prep: fp32 -> bf16, pre-swizzled (elem k ^= (row&7)<<3) for MFMA staging.
//    W1/W2 also transposed to [n][k].
__global__ __launch_bounds__(256) void k_prep(
        const float* __restrict__ x, const float* __restrict__ W1, const float* __restrict__ W2,
        u16* __restrict__ xb, u16* __restrict__ w1t, u16* __restrict__ w2t) {
    int i = blockIdx.x * 256 + threadIdx.x;
    if (i < XSZ) {
        int r = i >> 7, k = i & 127;
        xb[(r << 7) + (k ^ ((r & 7) << 3))] = f2bf(x[i]);
    } else if (i < XSZ + W1SZ) {
        int j = i - XSZ;
        int n = j >> 7, k = j & 127;
        w1t[(n << 7) + (k ^ ((n & 7) << 3))] = f2bf(W1[k * F1 + n]);
    } else if (i < XSZ + W1SZ + W2SZ) {
        int j = i - XSZ - W1SZ;
        int n = j >> 8, k = j & 255;
        w2t[(n << 8) + (k ^ ((n & 7) << 3))] = f2bf(W2[k * F2 + n]);
    }
}

// ---------------------------------------------------------------------------
// 3. GEMM1 (MFMA): h1[50000,256] = x @ W1, bf16 in/out, fp32 acc.
//    Block: 64 rows x 256 cols, 4 waves; wave w: cols w*64..w*64+63.
//    B frags held in registers (16 per wave, loaded once from L2-resident w1t).
__global__ __launch_bounds__(256) void k_gemm1(
        const u16* __restrict__ xb, const u16* __restrict__ w1t, u16* __restrict__ h1b) {
    __shared__ u16 As[64 * 128];   // 16KB, swizzled rows
    int r0 = blockIdx.x * 64;
    int t = threadIdx.x, w = t >> 6, l = t & 63;
    {   // linear 16KB stage (xb pre-swizzled)
        const uint4* gsrc = (const uint4*)(xb + (size_t)r0 * 128);
        uint4* lds = (uint4*)As;
        for (int i = t; i < 1024; i += 256) lds[i] = gsrc[i];
    }
    bf16x8 bfrag[4][4];   // [n][ks]
#pragma unroll
    for (int n = 0; n < 4; n++) {
        int col = w * 64 + n * 16 + (l & 15);
        const u16* wrow = w1t + col * 128;
        int swz = (col & 7) << 3;
#pragma unroll
        for (int ks = 0; ks < 4; ks++)
            bfrag[n][ks] = *(const bf16x8*)(wrow + ((ks * 32 + (l >> 4) * 8) ^ swz));
    }
    __syncthreads();
    f32x4 z = {0.f, 0.f, 0.f, 0.f};
    f32x4 acc[4][4];
#pragma unroll
    for (int m = 0; m < 4; m++)
#pragma unroll
        for (int n = 0; n < 4; n++) acc[m][n] = z;
#pragma unroll
    for (int ks = 0; ks < 4; ks++) {
#pragma unroll
        for (int m = 0; m < 4; m++) {
            int row = m * 16 + (l & 15);
            bf16x8 a = *(const bf16x8*)(As + row * 128 +
                                        ((ks * 32 + (l >> 4) * 8) ^ ((row & 7) << 3)));
#pragma unroll
            for (int n = 0; n < 4; n++)
                acc[m][n] = __builtin_amdgcn_mfma_f32_16x16x32_bf16(a, bfrag[n][ks], acc[m][n], 0, 0, 0);
        }
    }
#pragma unroll
    for (int m = 0; m < 4; m++) {
        int rbase = r0 + m * 16 + (l >> 4) * 4;
#pragma unroll
        for (int n = 0; n < 4; n++) {
            int col = w * 64 + n * 16 + (l & 15);
#pragma unroll
            for (int r = 0; r < 4; r++) {
                int rr = rbase + r;
                if (rr < N) h1b[(size_t)rr * 256 + (col ^ ((rr & 7) << 3))] = f2bf(acc[m][n][r]);
            }
        }
    }
}

// ---------------------------------------------------------------------------
// 4. alpha1 from h1b: one wave per row; lane loads stored elems 4l..4l+3.
__global__ __launch_bounds__(256) void k_alpha1(
        const u16* __restrict__ h1b, const float* __restrict__ as1, const float* __restrict__ ad1,
        float* __restrict__ asrc1, float* __restrict__ adst1) {
    int row = blockIdx.x * 4 + (threadIdx.x >> 6);
    if (row >= N) return;
    int l = threadIdx.x & 63;
    int swz = (row & 7) << 3;
    uint2 v = *(const uint2*)(h1b + (size_t)row * 256 + 4 * l);
    int c0 = (4 * l) ^ swz;   // logical col of elem 0; 4 consecutive
    float f0 = bf2f((u16)(v.x & 0xffff)), f1 = bf2f((u16)(v.x >> 16));
    float f2 = bf2f((u16)(v.y & 0xffff)), f3 = bf2f((u16)(v.y >> 16));
    float ps = f0 * as1[c0] + f1 * as1[c0 + 1] + f2 * as1[c0 + 2] + f3 * as1[c0 + 3];
    float pd = f0 * ad1[c0] + f1 * ad1[c0 + 1] + f2 * ad1[c0 + 2] + f3 * ad1[c0 + 3];
    ps += __shfl_xor(ps, 1, 64);
    pd += __shfl_xor(pd, 1, 64);
    if (!(l & 1)) {
        int head = (l >> 1) ^ (swz >> 3);
        asrc1[(size_t)row * H1 + head] = ps;
        adst1[(size_t)row * H1 + head] = pd;
    }
}

// ---------------------------------------------------------------------------
// 5. Edge pass 1: block per dst; bf16 swizzled h1 gather; cooperative scores.
__global__ __launch_bounds__(256) void k_edge1(
        const int* __restrict__ rs, const int* __restrict__ csr,
        const u16* __restrict__ h1b, const float* __restrict__ asrc,
        const float* __restrict__ adst, const float* __restrict__ b1,
        u16* __restrict__ outb) {
    __shared__ int   s_sh[64];
    __shared__ float ws[64][33];
    int d = blockIdx.x;
    int t = threadIdx.x;
    int h8 = t >> 3, hs = t & 31;
    int beg = rs[d], end = rs[d + 1];
    float ad_sc = adst[(size_t)d * H1 + hs];
    float ads = adst[(size_t)d * H1 + h8];
    float wself = __expf(leaky(asrc[(size_t)d * H1 + h8] + ads));
    float den = wself;
    float acc = wself * bf2f(h1b[(size_t)d * 256 + (t ^ ((d & 7) << 3))]);
    for (int base = beg; base < end; base += 64) {
        int cnt = min(64, end - base);
        if (t < cnt) s_sh[t] = csr[base + t];
        __syncthreads();
        for (int j = t; j < cnt * 32; j += 256) {
            int i = j >> 5;
            int s = s_sh[i];
            ws[i][hs] = __expf(leaky(asrc[(size_t)s * H1 + hs] + ad_sc));
        }
        __syncthreads();
#pragma unroll 4
        for (int i = 0; i < cnt; i++) {
            float wv = ws[i][h8];
            int s = s_sh[i];
            den += wv;
            acc = fmaf(wv, bf2f(h1b[(size_t)s * 256 + (t ^ ((s & 7) << 3))]), acc);
        }
        __syncthreads();
    }
    outb[(size_t)d * 256 + (t ^ ((d & 7) << 3))] = f2bf(acc / (den + 1e-16f) + b1[t]);
}

// ---------------------------------------------------------------------------
// 6. GEMM2 (MFMA): h2[50000,64] = h1a @ W2. Block 64 rows, wave w: rows w*16..+15.
__global__ __launch_bounds__(256) void k_gemm2(
        const u16* __restrict__ ab, const u16* __restrict__ w2t, u16* __restrict__ h2b) {
    __shared__ u16 As[64 * 256];   // 32KB
    int r0 = blockIdx.x * 64;
    int t = threadIdx.x, w = t >> 6, l = t & 63;
    {
        const uint4* gsrc = (const uint4*)(ab + (size_t)r0 * 256);
        uint4* lds = (uint4*)As;
        for (int i = t; i < 2048; i += 256) lds[i] = gsrc[i];
    }
    __syncthreads();
    f32x4 z = {0.f, 0.f, 0.f, 0.f};
    f32x4 acc[4];
#pragma unroll
    for (int n = 0; n < 4; n++) acc[n] = z;
    int row = w * 16 + (l & 15);
    int swzA = (row & 7) << 3;
#pragma unroll
    for (int ks = 0; ks < 8; ks++) {
        int ka = ks * 32 + (l >> 4) * 8;
        bf16x8 a = *(const bf16x8*)(As + row * 256 + (ka ^ swzA));
#pragma unroll
        for (int n = 0; n < 4; n++) {
            int col = n * 16 + (l & 15);
            bf16x8 b = *(const bf16x8*)(w2t + col * 256 + (ka ^ ((col & 7) << 3)));
            acc[n] = __builtin_amdgcn_mfma_f32_16x16x32_bf16(a, b, acc[n], 0, 0, 0);
        }
    }
#pragma unroll
    for (int n = 0; n < 4; n++) {
        int col = n * 16 + (l & 15);
#pragma unroll
        for (int r = 0; r < 4; r++) {
            int rr = r0 + w * 16 + (l >> 4) * 4 + r;
            if (rr < N) h2b[(size_t)rr * F2 + col] = f2bf(acc[n][r]);
        }
    }
}

// ---------------------------------------------------------------------------
// 7. alpha2 from h2b (linear): one wave per row.
__global__ __launch_bounds__(256) void k_alpha2(
        const u16* __restrict__ h2b, const float* __restrict__ a2s, const float* __restrict__ a2d,
        float* __restrict__ asrc2, float* __restrict__ adst2) {
    int row = blockIdx.x * 4 + (threadIdx.x >> 6);
    if (row >= N) return;
    int l = threadIdx.x & 63;
    float f = bf2f(h2b[(size_t)row * F2 + l]);
    float ps = f * a2s[l], pd = f * a2d[l];
#pragma unroll
    for (int o = 1; o < 64; o <<= 1) {
        ps += __shfl_xor(ps, o, 64);
        pd += __shfl_xor(pd, o, 64);
    }
    if (l == 0) { asrc2[row] = ps; adst2[row] = pd; }
}

// ---------------------------------------------------------------------------
// 8. Edge pass 2: one wave per node; bf16 h2 gather; sigmoid out (fp32).
__global__ __launch_bounds__(256) void k_edge2(
        const int* __restrict__ rs, const int* __restrict__ csr,
        const u16* __restrict__ h2b, const float* __restrict__ asrc,
        const float* __restrict__ adst, const float* __restrict__ b2,
        float* __restrict__ out) {
    int d = blockIdx.x * 4 + (threadIdx.x >> 6);
    int lane = threadIdx.x & 63;
    if (d >= N) return;
    int beg = rs[d], end = rs[d + 1];
    float ad = adst[d];
    float den = __expf(leaky(asrc[d] + ad));
    float acc = den * bf2f(h2b[(size_t)d * F2 + lane]);
    for (int base = beg; base < end; base += 64) {
        int cnt = min(64, end - base);
        int s = (lane < cnt) ? csr[base + lane] : 0;
        float wv = (lane < cnt) ? __expf(leaky(asrc[s] + ad)) : 0.f;
        for (int i = 0; i < cnt; i++) {
            float wi = __shfl(wv, i, 64);
            int   si = __shfl(s, i, 64);
            den += wi;
            acc = fmaf(wi, bf2f(h2b[(size_t)si * F2 + lane]), acc);
        }
    }
    float v = acc / (den + 1e-16f) + b2[lane];
    out[(size_t)d * F2 + lane] = 1.f / (1.f + __expf(-v));
}

// ---------------------------------------------------------------------------
extern "C" void kernel_launch(void* const* d_in, const int* in_sizes, int n_in,
                              void* d_out, int out_size, void* d_ws, size_t ws_size,
                              hipStream_t stream) {
    const float* x   = (const float*)d_in[0];
    const void*  ei  = d_in[1];
    const float* W1  = (const float*)d_in[2];
    const float* as1 = (const float*)d_in[3];
    const float* ad1 = (const float*)d_in[4];
    const float* b1  = (const float*)d_in[5];
    const float* W2  = (const float*)d_in[6];
    const float* a2s = (const float*)d_in[7];
    const float* a2d = (const float*)d_in[8];
    const float* b2  = (const float*)d_in[9];
    float* out = (float*)d_out;

    char* wp = (char*)d_ws;
    size_t off = 0;
    auto alloc = [&](size_t bytes) {
        void* p = wp + off;
        off = (off + bytes + 255) & ~(size_t)255;
        return p;
    };
    int* flag  = (int*)alloc(4);
    int* deg   = (int*)alloc((size_t)N * 4);
    int* fill  = (int*)alloc((size_t)N * 4);
    int* rs    = (int*)alloc((size_t)(N + 1) * 4);
    int* bsum  = (int*)alloc((size_t)NB * 4);
    int* csr   = (int*)alloc((size_t)E * 4);
    u16* xb    = (u16*)alloc((size_t)NPAD * F0 * 2);
    u16* w1t   = (u16*)alloc((size_t)W1SZ * 2);
    u16* w2t   = (u16*)alloc((size_t)W2SZ * 2);
    u16* h1b   = (u16*)alloc((size_t)NPAD * F1 * 2);
    u16* h1ab  = (u16*)alloc((size_t)NPAD * F1 * 2);
    u16* h2b   = (u16*)alloc((size_t)NPAD * F2 * 2);
    float* asrc1 = (float*)alloc((size_t)N * H1 * 4);
    float* adst1 = (float*)alloc((size_t)N * H1 * 4);
    float* asrc2 = (float*)alloc((size_t)N * 4);
    float* adst2 = (float*)alloc((size_t)N * 4);

    hipMemsetAsync(deg, 0, (size_t)N * 4, stream);
    hipMemsetAsync(fill, 0, (size_t)N * 4, stream);

    k_detect<<<1, 1024, 0, stream>>>((const unsigned long long*)ei, flag);
    k_count<<<(E + 255) / 256, 256, 0, stream>>>(ei, flag, deg);
    k_bsum<<<NB, 256, 0, stream>>>(deg, bsum);
    k_bscan<<<1, 256, 0, stream>>>(bsum, rs + N);
    k_rs<<<NB, 256, 0, stream>>>(deg, bsum, rs);
    k_scatter<<<(E + 255) / 256, 256, 0, stream>>>(ei, flag, rs, fill, csr);

    k_prep<<<(XSZ + W1SZ + W2SZ + 255) / 256, 256, 0, stream>>>(x, W1, W2, xb, w1t, w2t);
    k_gemm1<<<NPAD / 64, 256, 0, stream>>>(xb, w1t, h1b);
    k_alpha1<<<(N + 3) / 4, 256, 0, stream>>>(h1b, as1, ad1, asrc1, adst1);
    k_edge1<<<N, 256, 0, stream>>>(rs, csr, h1b, asrc1, adst1, b1, h1ab);
    k_gemm2<<<NPAD / 64, 256, 0, stream>>>(h1ab, w2t, h2b);
    k_alpha2<<<(N + 3) / 4, 256, 0, stream>>>(h2b, a2s, a2d, asrc2, adst2);
    k_edge2<<<(N + 3) / 4, 256, 0, stream>>>(rs, csr, h2b, asrc2, adst2, b2, out);
}

// Round 4
// 246.158 us; speedup vs baseline: 2.9212x; 1.3526x over previous
//
#include <hip/hip_runtime.h>
#include <hip/hip_bf16.h>

constexpr int N  = 50000;
constexpr int E  = 800000;
constexpr int F0 = 128;
constexpr int H1 = 32;
constexpr int F1 = 256;
constexpr int F2 = 64;
constexpr int NB = (N + 255) / 256;        // 196 scan blocks
constexpr int NPAD = 782 * 64;             // 50048
constexpr int W1SZ = F0 * F1;              // 32768
constexpr int W2SZ = F1 * F2;              // 16384
constexpr float NEG_SLOPE = 0.2f;

typedef unsigned short u16;
typedef unsigned int   u32;
typedef __attribute__((ext_vector_type(8))) short bf16x8;
typedef __attribute__((ext_vector_type(4))) float f32x4;

__device__ __forceinline__ float leaky(float e) {
    return fmaxf(e, 0.f) + NEG_SLOPE * fminf(e, 0.f);
}
__device__ __forceinline__ float bf2f(u16 u) {
    u32 v = ((u32)u) << 16;
    return __builtin_bit_cast(float, v);
}
__device__ __forceinline__ u16 f2bf(float f) {
    u32 u = __builtin_bit_cast(u32, f);
    u += 0x7fffu + ((u >> 16) & 1u);
    return (u16)(u >> 16);
}
__device__ __forceinline__ u32 pack2(float a, float b) {
    return (u32)f2bf(a) | ((u32)f2bf(b) << 16);
}
// unpack uint into 2 floats (lo, hi)
__device__ __forceinline__ void up2(u32 v, float& lo, float& hi) {
    lo = __builtin_bit_cast(float, v << 16);
    hi = __builtin_bit_cast(float, v & 0xffff0000u);
}

// ---------------------------------------------------------------------------
// 0. edge_index dtype detect (int64 vs int32)
__global__ void k_detect(const unsigned long long* __restrict__ p, int* __restrict__ flag) {
    __shared__ int bad;
    if (threadIdx.x == 0) bad = 0;
    __syncthreads();
    unsigned long long v = p[threadIdx.x];
    if (v >= (unsigned long long)N) atomicOr(&bad, 1);
    __syncthreads();
    if (threadIdx.x == 0) *flag = bad ? 0 : 1;
}
__device__ __forceinline__ int load_idx(const void* ei, long long i, int is64) {
    return is64 ? (int)((const long long*)ei)[i] : ((const int*)ei)[i];
}

// ---------------------------------------------------------------------------
// 1. CSR build by dst
__global__ void k_count(const void* __restrict__ ei, const int* __restrict__ flag,
                        int* __restrict__ deg) {
    int e = blockIdx.x * blockDim.x + threadIdx.x;
    if (e >= E) return;
    int dst = load_idx(ei, (long long)E + e, *flag);
    atomicAdd(&deg[dst], 1);
}
__global__ __launch_bounds__(256) void k_bsum(const int* __restrict__ deg, int* __restrict__ bsum) {
    int b = blockIdx.x, t = threadIdx.x, i = b * 256 + t;
    int v = (i < N) ? deg[i] : 0;
#pragma unroll
    for (int o = 1; o < 64; o <<= 1) v += __shfl_xor(v, o, 64);
    __shared__ int sw[4];
    if ((t & 63) == 0) sw[t >> 6] = v;
    __syncthreads();
    if (t == 0) bsum[b] = sw[0] + sw[1] + sw[2] + sw[3];
}
__global__ __launch_bounds__(256) void k_bscan(int* __restrict__ bsum, int* __restrict__ rsN) {
    int t = threadIdx.x, lane = t & 63, wy = t >> 6;
    int v = (t < NB) ? bsum[t] : 0;
    int inc = v;
#pragma unroll
    for (int o = 1; o < 64; o <<= 1) { int u = __shfl_up(inc, o, 64); if (lane >= o) inc += u; }
    __shared__ int wtot[4];
    if (lane == 63) wtot[wy] = inc;
    __syncthreads();
    int offs = 0;
    for (int k = 0; k < wy; k++) offs += wtot[k];
    int excl = offs + inc - v;
    if (t < NB) bsum[t] = excl;
    if (t == NB - 1) *rsN = excl + v;
}
__global__ __launch_bounds__(256) void k_rs(const int* __restrict__ deg,
                                            const int* __restrict__ bsum, int* __restrict__ rs) {
    int b = blockIdx.x, t = threadIdx.x, i = b * 256 + t;
    int lane = t & 63, wy = t >> 6;
    int v = (i < N) ? deg[i] : 0;
    int inc = v;
#pragma unroll
    for (int o = 1; o < 64; o <<= 1) { int u = __shfl_up(inc, o, 64); if (lane >= o) inc += u; }
    __shared__ int wtot[4];
    if (lane == 63) wtot[wy] = inc;
    __syncthreads();
    int offs = bsum[b];
    for (int k = 0; k < wy; k++) offs += wtot[k];
    if (i < N) rs[i] = offs + inc - v;
}
__global__ void k_scatter(const void* __restrict__ ei, const int* __restrict__ flag,
                          const int* __restrict__ rs, int* __restrict__ fill,
                          int* __restrict__ csr) {
    int e = blockIdx.x * blockDim.x + threadIdx.x;
    if (e >= E) return;
    int is64 = *flag;
    int src = load_idx(ei, e, is64);
    int dst = load_idx(ei, (long long)E + e, is64);
    int pos = rs[dst] + atomicAdd(&fill[dst], 1);
    csr[pos] = src;
}

// ---------------------------------------------------------------------------
// 2. Prep weights: fp32 -> bf16, transposed [n][k], pre-swizzled (k ^= (n&7)<<3).
__global__ __launch_bounds__(256) void k_prepw(
        const float* __restrict__ W1, const float* __restrict__ W2,
        u16* __restrict__ w1t, u16* __restrict__ w2t) {
    int i = blockIdx.x * 256 + threadIdx.x;
    if (i < W1SZ) {
        int n = i >> 7, k = i & 127;
        w1t[(n << 7) + (k ^ ((n & 7) << 3))] = f2bf(W1[k * F1 + n]);
    } else if (i < W1SZ + W2SZ) {
        int j = i - W1SZ;
        int n = j >> 8, k = j & 255;
        w2t[(n << 8) + (k ^ ((n & 7) << 3))] = f2bf(W2[k * F2 + n]);
    }
}

// ---------------------------------------------------------------------------
// 3. GEMM1 (MFMA): h1[N,256] = x @ W1; x converted fp32->bf16 + swizzled
//    inline during LDS staging. Block 64 rows x 256 cols, 4 waves.
__global__ __launch_bounds__(256) void k_gemm1(
        const float* __restrict__ x, const u16* __restrict__ w1t, u16* __restrict__ h1b) {
    __shared__ u16 As[64 * 128];   // 16KB, swizzled rows
    int r0 = blockIdx.x * 64;
    int t = threadIdx.x, w = t >> 6, l = t & 63;
    {   // stage: thread t -> row t>>2, 32 cols at (t&3)*32
        int r = t >> 2, k0 = (t & 3) * 32, rr = r0 + r;
        int swz = (r & 7) << 3;
        float4 f[8];
        if (rr < N) {
            const float4* px = (const float4*)(x + (size_t)rr * F0 + k0);
#pragma unroll
            for (int j = 0; j < 8; j++) f[j] = px[j];
        } else {
#pragma unroll
            for (int j = 0; j < 8; j++) f[j] = make_float4(0.f, 0.f, 0.f, 0.f);
        }
#pragma unroll
        for (int g = 0; g < 4; g++) {
            uint4 st;
            st.x = pack2(f[2 * g].x, f[2 * g].y);
            st.y = pack2(f[2 * g].z, f[2 * g].w);
            st.z = pack2(f[2 * g + 1].x, f[2 * g + 1].y);
            st.w = pack2(f[2 * g + 1].z, f[2 * g + 1].w);
            *(uint4*)(As + r * 128 + ((k0 + 8 * g) ^ swz)) = st;
        }
    }
    bf16x8 bfrag[4][4];
#pragma unroll
    for (int n = 0; n < 4; n++) {
        int col = w * 64 + n * 16 + (l & 15);
        const u16* wrow = w1t + col * 128;
        int swz = (col & 7) << 3;
#pragma unroll
        for (int ks = 0; ks < 4; ks++)
            bfrag[n][ks] = *(const bf16x8*)(wrow + ((ks * 32 + (l >> 4) * 8) ^ swz));
    }
    __syncthreads();
    f32x4 z = {0.f, 0.f, 0.f, 0.f};
    f32x4 acc[4][4];
#pragma unroll
    for (int m = 0; m < 4; m++)
#pragma unroll
        for (int n = 0; n < 4; n++) acc[m][n] = z;
#pragma unroll
    for (int ks = 0; ks < 4; ks++) {
#pragma unroll
        for (int m = 0; m < 4; m++) {
            int row = m * 16 + (l & 15);
            bf16x8 a = *(const bf16x8*)(As + row * 128 +
                                        ((ks * 32 + (l >> 4) * 8) ^ ((row & 7) << 3)));
#pragma unroll
            for (int n = 0; n < 4; n++)
                acc[m][n] = __builtin_amdgcn_mfma_f32_16x16x32_bf16(a, bfrag[n][ks], acc[m][n], 0, 0, 0);
        }
    }
#pragma unroll
    for (int m = 0; m < 4; m++) {
        int rbase = r0 + m * 16 + (l >> 4) * 4;
#pragma unroll
        for (int n = 0; n < 4; n++) {
            int col = w * 64 + n * 16 + (l & 15);
#pragma unroll
            for (int r = 0; r < 4; r++) {
                int rr = rbase + r;
                if (rr < N) h1b[(size_t)rr * 256 + (col ^ ((rr & 7) << 3))] = f2bf(acc[m][n][r]);
            }
        }
    }
}

// ---------------------------------------------------------------------------
// 4. alpha1 from h1b: one wave per row.
__global__ __launch_bounds__(256) void k_alpha1(
        const u16* __restrict__ h1b, const float* __restrict__ as1, const float* __restrict__ ad1,
        float* __restrict__ asrc1, float* __restrict__ adst1) {
    int row = blockIdx.x * 4 + (threadIdx.x >> 6);
    if (row >= N) return;
    int l = threadIdx.x & 63;
    int swz = (row & 7) << 3;
    uint2 v = *(const uint2*)(h1b + (size_t)row * 256 + 4 * l);
    int c0 = (4 * l) ^ swz;
    float f0, f1, f2, f3;
    up2(v.x, f0, f1); up2(v.y, f2, f3);
    float ps = f0 * as1[c0] + f1 * as1[c0 + 1] + f2 * as1[c0 + 2] + f3 * as1[c0 + 3];
    float pd = f0 * ad1[c0] + f1 * ad1[c0 + 1] + f2 * ad1[c0 + 2] + f3 * ad1[c0 + 3];
    ps += __shfl_xor(ps, 1, 64);
    pd += __shfl_xor(pd, 1, 64);
    if (!(l & 1)) {
        int head = (l >> 1) ^ (swz >> 3);
        asrc1[(size_t)row * H1 + head] = ps;
        adst1[(size_t)row * H1 + head] = pd;
    }
}

// ---------------------------------------------------------------------------
// 5. Edge pass 1: ONE WAVE per dst node. Lane l owns logical channels 4l..4l+3
//    (uint2 = 8B/lane, 512B/row in one wave instruction). Edges in pairs:
//    half-wave A computes 32 head scores of edge A, half-wave B of edge B.
__global__ __launch_bounds__(256) void k_edge1(
        const int* __restrict__ rs, const int* __restrict__ csr,
        const u16* __restrict__ h1b, const float* __restrict__ asrc,
        const float* __restrict__ adst, const float* __restrict__ b1,
        u16* __restrict__ outb) {
    int d = blockIdx.x * 4 + (threadIdx.x >> 6);
    if (d >= N) return;
    int l = threadIdx.x & 63;
    int hl = l >> 1;                         // accum head of this lane
    int beg = rs[d], end = rs[d + 1];
    float ad_sc = adst[(size_t)d * H1 + (l & 31)];   // score head for this lane
    // self loop
    float wself = __expf(leaky(asrc[(size_t)d * H1 + hl] + adst[(size_t)d * H1 + hl]));
    float den = wself;
    int swzD = (d & 7) << 3;
    uint2 vd = *(const uint2*)(h1b + (size_t)d * 256 + ((4 * l) ^ swzD));
    float a0, a1, a2, a3;
    up2(vd.x, a0, a1); up2(vd.y, a2, a3);
    float c0 = wself * a0, c1 = wself * a1, c2 = wself * a2, c3 = wself * a3;

    for (int base = beg; base < end; base += 64) {
        int cnt = min(64, end - base);
        int s_ch = (base + l < end) ? csr[base + l] : 0;
        for (int i = 0; i < cnt; i += 2) {
            int sA = __shfl(s_ch, i, 64);
            int sB = __shfl(s_ch, i + 1, 64);
            int sS = (l < 32) ? sA : sB;
            float e = leaky(asrc[(size_t)sS * H1 + (l & 31)] + ad_sc);
            bool valid = (l < 32) | (i + 1 < cnt);
            float wsc = valid ? __expf(e) : 0.f;
            float wA = __shfl(wsc, hl, 64);
            float wB = __shfl(wsc, 32 + hl, 64);
            den += wA + wB;
            uint2 va = *(const uint2*)(h1b + (size_t)sA * 256 + ((4 * l) ^ ((sA & 7) << 3)));
            uint2 vb = *(const uint2*)(h1b + (size_t)sB * 256 + ((4 * l) ^ ((sB & 7) << 3)));
            float t0, t1, t2, t3;
            up2(va.x, t0, t1); up2(va.y, t2, t3);
            c0 = fmaf(wA, t0, c0); c1 = fmaf(wA, t1, c1);
            c2 = fmaf(wA, t2, c2); c3 = fmaf(wA, t3, c3);
            up2(vb.x, t0, t1); up2(vb.y, t2, t3);
            c0 = fmaf(wB, t0, c0); c1 = fmaf(wB, t1, c1);
            c2 = fmaf(wB, t2, c2); c3 = fmaf(wB, t3, c3);
        }
    }
    float inv = 1.f / (den + 1e-16f);
    int ch = 4 * l;
    uint2 st;
    st.x = pack2(c0 * inv + b1[ch], c1 * inv + b1[ch + 1]);
    st.y = pack2(c2 * inv + b1[ch + 2], c3 * inv + b1[ch + 3]);
    *(uint2*)(outb + (size_t)d * 256 + (ch ^ swzD)) = st;
}

// ---------------------------------------------------------------------------
// 6. GEMM2 (MFMA): h2[N,64] = h1a @ W2. Block 64 rows; wave w: rows w*16..+15.
__global__ __launch_bounds__(256) void k_gemm2(
        const u16* __restrict__ ab, const u16* __restrict__ w2t, u16* __restrict__ h2b) {
    __shared__ u16 As[64 * 256];
    int r0 = blockIdx.x * 64;
    int t = threadIdx.x, w = t >> 6, l = t & 63;
    {
        const uint4* gsrc = (const uint4*)(ab + (size_t)r0 * 256);
        uint4* lds = (uint4*)As;
        for (int i = t; i < 2048; i += 256) lds[i] = gsrc[i];
    }
    __syncthreads();
    f32x4 z = {0.f, 0.f, 0.f, 0.f};
    f32x4 acc[4];
#pragma unroll
    for (int n = 0; n < 4; n++) acc[n] = z;
    int row = w * 16 + (l & 15);
    int swzA = (row & 7) << 3;
#pragma unroll
    for (int ks = 0; ks < 8; ks++) {
        int ka = ks * 32 + (l >> 4) * 8;
        bf16x8 a = *(const bf16x8*)(As + row * 256 + (ka ^ swzA));
#pragma unroll
        for (int n = 0; n < 4; n++) {
            int col = n * 16 + (l & 15);
            bf16x8 b = *(const bf16x8*)(w2t + col * 256 + (ka ^ ((col & 7) << 3)));
            acc[n] = __builtin_amdgcn_mfma_f32_16x16x32_bf16(a, b, acc[n], 0, 0, 0);
        }
    }
#pragma unroll
    for (int n = 0; n < 4; n++) {
        int col = n * 16 + (l & 15);
#pragma unroll
        for (int r = 0; r < 4; r++) {
            int rr = r0 + w * 16 + (l >> 4) * 4 + r;
            if (rr < N) h2b[(size_t)rr * F2 + col] = f2bf(acc[n][r]);
        }
    }
}

// ---------------------------------------------------------------------------
// 7. alpha2 from h2b: one wave per row.
__global__ __launch_bounds__(256) void k_alpha2(
        const u16* __restrict__ h2b, const float* __restrict__ a2s, const float* __restrict__ a2d,
        float* __restrict__ asrc2, float* __restrict__ adst2) {
    int row = blockIdx.x * 4 + (threadIdx.x >> 6);
    if (row >= N) return;
    int l = threadIdx.x & 63;
    float f = bf2f(h2b[(size_t)row * F2 + l]);
    float ps = f * a2s[l], pd = f * a2d[l];
#pragma unroll
    for (int o = 1; o < 64; o <<= 1) {
        ps += __shfl_xor(ps, o, 64);
        pd += __shfl_xor(pd, o, 64);
    }
    if (l == 0) { asrc2[row] = ps; adst2[row] = pd; }
}

// ---------------------------------------------------------------------------
// 8. Edge pass 2: ONE WAVE per node; quarter-wave per edge (4 edges/iter).
//    Lane l: quarter q=l>>4, channels 4*(l&15)..+3 (uint2). H=1.
__global__ __launch_bounds__(256) void k_edge2(
        const int* __restrict__ rs, const int* __restrict__ csr,
        const u16* __restrict__ h2b, const float* __restrict__ asrc,
        const float* __restrict__ adst, const float* __restrict__ b2,
        float* __restrict__ out) {
    int d = blockIdx.x * 4 + (threadIdx.x >> 6);
    if (d >= N) return;
    int l = threadIdx.x & 63;
    int q = l >> 4, c4 = (l & 15) * 4;
    int beg = rs[d], end = rs[d + 1];
    float add_ = adst[d];
    float wself = __expf(leaky(asrc[d] + add_));
    float wq0 = (q == 0) ? wself : 0.f;
    float den = wq0;
    uint2 vd = *(const uint2*)(h2b + (size_t)d * F2 + c4);
    float a0, a1, a2, a3;
    up2(vd.x, a0, a1); up2(vd.y, a2, a3);
    float c0 = wq0 * a0, c1 = wq0 * a1, c2 = wq0 * a2, c3 = wq0 * a3;

    for (int base = beg; base < end; base += 64) {
        int cnt = min(64, end - base);
        bool in = (base + l < end);
        int s_ch = in ? csr[base + l] : 0;
        float w_l = in ? __expf(leaky(asrc[s_ch] + add_)) : 0.f;
        for (int i = 0; i < cnt; i += 4) {
            int e = i + q;
            float wi = __shfl(w_l, e, 64);
            int   si = __shfl(s_ch, e, 64);
            wi = (e < cnt) ? wi : 0.f;
            uint2 v = *(const uint2*)(h2b + (size_t)si * F2 + c4);
            float t0, t1, t2, t3;
            up2(v.x, t0, t1); up2(v.y, t2, t3);
            c0 = fmaf(wi, t0, c0); c1 = fmaf(wi, t1, c1);
            c2 = fmaf(wi, t2, c2); c3 = fmaf(wi, t3, c3);
            den += wi;
        }
    }
    // cross-quarter reduce (lanes l, l^16, l^32, l^48 share channel group)
    den += __shfl_xor(den, 16, 64); den += __shfl_xor(den, 32, 64);
    c0 += __shfl_xor(c0, 16, 64);   c0 += __shfl_xor(c0, 32, 64);
    c1 += __shfl_xor(c1, 16, 64);   c1 += __shfl_xor(c1, 32, 64);
    c2 += __shfl_xor(c2, 16, 64);   c2 += __shfl_xor(c2, 32, 64);
    c3 += __shfl_xor(c3, 16, 64);   c3 += __shfl_xor(c3, 32, 64);
    if (q == 0) {
        float inv = 1.f / (den + 1e-16f);
        float4 o;
        o.x = 1.f / (1.f + __expf(-(c0 * inv + b2[c4])));
        o.y = 1.f / (1.f + __expf(-(c1 * inv + b2[c4 + 1])));
        o.z = 1.f / (1.f + __expf(-(c2 * inv + b2[c4 + 2])));
        o.w = 1.f / (1.f + __expf(-(c3 * inv + b2[c4 + 3])));
        *(float4*)(out + (size_t)d * F2 + c4) = o;
    }
}

// ---------------------------------------------------------------------------
extern "C" void kernel_launch(void* const* d_in, const int* in_sizes, int n_in,
                              void* d_out, int out_size, void* d_ws, size_t ws_size,
                              hipStream_t stream) {
    const float* x   = (const float*)d_in[0];
    const void*  ei  = d_in[1];
    const float* W1  = (const float*)d_in[2];
    const float* as1 = (const float*)d_in[3];
    const float* ad1 = (const float*)d_in[4];
    const float* b1  = (const float*)d_in[5];
    const float* W2  = (const float*)d_in[6];
    const float* a2s = (const float*)d_in[7];
    const float* a2d = (const float*)d_in[8];
    const float* b2  = (const float*)d_in[9];
    float* out = (float*)d_out;

    char* wp = (char*)d_ws;
    size_t off = 0;
    auto alloc = [&](size_t bytes) {
        void* p = wp + off;
        off = (off + bytes + 255) & ~(size_t)255;
        return p;
    };
    int* flag  = (int*)alloc(4);
    int* deg   = (int*)alloc((size_t)N * 4);
    int* fill  = (int*)alloc((size_t)N * 4);
    int* rs    = (int*)alloc((size_t)(N + 1) * 4);
    int* bsum  = (int*)alloc((size_t)NB * 4);
    int* csr   = (int*)alloc((size_t)E * 4);
    u16* w1t   = (u16*)alloc((size_t)W1SZ * 2);
    u16* w2t   = (u16*)alloc((size_t)W2SZ * 2);
    u16* h1b   = (u16*)alloc((size_t)NPAD * F1 * 2);
    u16* h1ab  = (u16*)alloc((size_t)NPAD * F1 * 2);
    u16* h2b   = (u16*)alloc((size_t)NPAD * F2 * 2);
    float* asrc1 = (float*)alloc((size_t)N * H1 * 4);
    float* adst1 = (float*)alloc((size_t)N * H1 * 4);
    float* asrc2 = (float*)alloc((size_t)N * 4);
    float* adst2 = (float*)alloc((size_t)N * 4);

    hipMemsetAsync(deg, 0, (size_t)N * 4, stream);
    hipMemsetAsync(fill, 0, (size_t)N * 4, stream);

    k_detect<<<1, 1024, 0, stream>>>((const unsigned long long*)ei, flag);
    k_count<<<(E + 255) / 256, 256, 0, stream>>>(ei, flag, deg);
    k_bsum<<<NB, 256, 0, stream>>>(deg, bsum);
    k_bscan<<<1, 256, 0, stream>>>(bsum, rs + N);
    k_rs<<<NB, 256, 0, stream>>>(deg, bsum, rs);
    k_scatter<<<(E + 255) / 256, 256, 0, stream>>>(ei, flag, rs, fill, csr);

    k_prepw<<<(W1SZ + W2SZ + 255) / 256, 256, 0, stream>>>(W1, W2, w1t, w2t);
    k_gemm1<<<NPAD / 64, 256, 0, stream>>>(x, w1t, h1b);
    k_alpha1<<<(N + 3) / 4, 256, 0, stream>>>(h1b, as1, ad1, asrc1, adst1);
    k_edge1<<<(N + 3) / 4, 256, 0, stream>>>(rs, csr, h1b, asrc1, adst1, b1, h1ab);
    k_gemm2<<<NPAD / 64, 256, 0, stream>>>(h1ab, w2t, h2b);
    k_alpha2<<<(N + 3) / 4, 256, 0, stream>>>(h2b, a2s, a2d, asrc2, adst2);
    k_edge2<<<(N + 3) / 4, 256, 0, stream>>>(rs, csr, h2b, asrc2, adst2, b2, out);
}